// Round 8
// baseline (392.888 us; speedup 1.0000x reference)
//
#include <hip/hip_runtime.h>
#include <math.h>

#define H 128

typedef _Float16 half8 __attribute__((ext_vector_type(8)));
typedef _Float16 half4 __attribute__((ext_vector_type(4)));
typedef float f32x16 __attribute__((ext_vector_type(16)));

// ---------------- CSR build ----------------

__global__ __launch_bounds__(256) void zero_ints(int* __restrict__ p, int n) {
    int i = blockIdx.x * 256 + threadIdx.x;
    if (i < n) p[i] = 0;
}

__global__ __launch_bounds__(256) void hist_deg(const int* __restrict__ ei, int E,
                                                int* __restrict__ deg) {
    int e = blockIdx.x * 256 + threadIdx.x;
    if (e < E) atomicAdd(&deg[ei[E + e]], 1);  // dst row of edge_index
}

__global__ __launch_bounds__(256) void block_sums(const int* __restrict__ deg,
                                                  int* __restrict__ bsum, int N) {
    __shared__ int part[4];
    int tid = threadIdx.x;
    int i = blockIdx.x * 256 + tid;
    int v = (i < N) ? deg[i] : 0;
#pragma unroll
    for (int off = 32; off > 0; off >>= 1) v += __shfl_down(v, off, 64);
    if ((tid & 63) == 0) part[tid >> 6] = v;
    __syncthreads();
    if (tid == 0) bsum[blockIdx.x] = part[0] + part[1] + part[2] + part[3];
}

__global__ __launch_bounds__(64) void scan_bsum(const int* __restrict__ bsum,
                                                int* __restrict__ bbase, int NB,
                                                int* __restrict__ totalOut) {
    int lane = threadIdx.x;
    int base = 0;
    for (int s0 = 0; s0 < NB; s0 += 64) {
        int i = s0 + lane;
        int v = (i < NB) ? bsum[i] : 0;
        int incl = v;
#pragma unroll
        for (int off = 1; off < 64; off <<= 1) {
            int t = __shfl_up(incl, off, 64);
            if (lane >= off) incl += t;
        }
        if (i < NB) bbase[i] = base + incl - v;
        base += __shfl(incl, 63, 64);
    }
    if (lane == 0) *totalOut = base;  // offsets[N] = E
}

__global__ __launch_bounds__(256) void scan_within(const int* __restrict__ deg,
                                                   const int* __restrict__ bbase,
                                                   int* __restrict__ offsets, int N) {
    __shared__ int buf[256];
    int tid = threadIdx.x;
    int i = blockIdx.x * 256 + tid;
    int v = (i < N) ? deg[i] : 0;
    int incl = v;
    buf[tid] = v;
    __syncthreads();
#pragma unroll
    for (int off = 1; off < 256; off <<= 1) {
        int t = (tid >= off) ? buf[tid - off] : 0;
        __syncthreads();
        incl += t;
        buf[tid] = incl;
        __syncthreads();
    }
    if (i < N) offsets[i] = bbase[blockIdx.x] + incl - v;  // exclusive scan
}

__global__ __launch_bounds__(256) void fill_adj(const int* __restrict__ ei, int E,
                                                const int* __restrict__ offsets,
                                                int* __restrict__ cursor,
                                                int* __restrict__ adj) {
    int e = blockIdx.x * 256 + threadIdx.x;
    if (e < E) {
        int s = ei[e];
        int d = ei[E + e];
        int pos = atomicAdd(&cursor[d], 1);
        adj[offsets[d] + pos] = s;
    }
}

// ---------------- query normalization ----------------

__global__ __launch_bounds__(128) void prep_query(const float* __restrict__ query,
                                                  float* __restrict__ qn) {
    int g = blockIdx.x;
    int f = threadIdx.x;
    float v = query[g * H + f];
    float ss = v * v;
#pragma unroll
    for (int off = 32; off > 0; off >>= 1) ss += __shfl_xor(ss, off, 64);
    __shared__ float part[2];
    if ((f & 63) == 0) part[f >> 6] = ss;
    __syncthreads();
    float tot = part[0] + part[1];
    qn[g * H + f] = v / fmaxf(sqrtf(tot), 1e-12f);
}

// ---------------- weight split into swizzled, K-chunked LDS images ----------
// mat order: Wl0,Wr0,Wl1,Wr1,Wl2,Wr2,Wlin. Address of (mat, kc, hl):
//   mat*32768 + kc*16384 + hl*8192 halves.
// Chunk image: [n][pos*8], pos = gp ^ (n&7), gp = granule within chunk.

__global__ __launch_bounds__(256) void prep_wsplit(const float* __restrict__ Wl,
                                                   const float* __restrict__ Wr,
                                                   const float* __restrict__ Wlin,
                                                   _Float16* __restrict__ img) {
    int gidx = blockIdx.x * 256 + threadIdx.x;
    if (gidx >= 7 * 128 * 16) return;
    int mat = gidx / 2048;
    int rem = gidx - mat * 2048;
    int n = rem >> 4;
    int g = rem & 15;  // global granule [0,16)
    const float* src = (mat == 6) ? Wlin
                     : ((mat & 1) ? Wr + (mat >> 1) * H * H : Wl + (mat >> 1) * H * H);
    const float* p = src + n * H + g * 8;
    half8 h, l;
#pragma unroll
    for (int j = 0; j < 8; ++j) {
        float v = p[j];
        _Float16 hh = (_Float16)v;
        h[j] = hh;
        l[j] = (_Float16)(v - (float)hh);
    }
    int kc = g >> 3, gp = g & 7;
    int pos = gp ^ (n & 7);
    size_t cbase = (((size_t)mat * 2 + kc) * 2) * 8192 + (size_t)n * 64 + pos * 8;
    *(half8*)(img + cbase) = h;         // hi
    *(half8*)(img + cbase + 8192) = l;  // lo
}

// ---------------- fused layer: gather-max + dual GEMM + bias + relu --------
// xout = relu(segmax(X) @ Wl^T + bias + X @ Wr^T), split-fp16 x3 MFMA.
// Block 256 = 4 waves; tile 64 rows x 128 cols.
// Phase G: per-block gather of its 64 rows' segment-max, written as split
//   hi/lo into the full-K swizzled LDS image sU (32 KB).
// Pass 0 (m@Wl): fragments from sU image; B chunks restaged per kc.
// Pass 1 (x@Wr): sU's first 16 KB reused as per-chunk x image.
// LDS: sU 32 KB + sB 32 KB = 64 KB -> 2 blocks/CU.

__global__ __launch_bounds__(256) void layer_fused(
    const float* __restrict__ X, const int* __restrict__ offsets,
    const int* __restrict__ adj, const _Float16* __restrict__ Bimg,
    const float* __restrict__ bias, float* __restrict__ xout, int N) {
    __shared__ __align__(16) _Float16 sU[16384];  // m image / x chunk image
    __shared__ __align__(16) _Float16 sB[16384];  // B chunk hi/lo

    int tid = threadIdx.x;
    int w = tid >> 6;
    int lane = tid & 63;
    int l31 = lane & 31;
    int lhi = lane >> 5;
    int ws = w >> 1;  // row stripe (32 rows)
    int wc = w & 1;   // col half (64 cols)
    int n0 = blockIdx.x * 64;

    const float4* X4 = (const float4*)X;

    // ---- Phase G: gather segment-max for rows n0..n0+63 ----
    {
        int f4 = tid & 31;
        int grp = tid >> 5;  // 8 groups, 8 nodes each
        for (int i = 0; i < 8; ++i) {
            int row = grp * 8 + i;
            int node = n0 + row;
            int nc = node < N ? node : N - 1;
            int e0 = offsets[nc], e1 = offsets[nc + 1];
            float4 b = make_float4(0.f, 0.f, 0.f, 0.f);
            if (node < N && e1 > e0) {
                float4 acc[8];
#pragma unroll
                for (int u = 0; u < 8; ++u)
                    acc[u] = make_float4(-INFINITY, -INFINITY, -INFINITY, -INFINITY);
                for (int base = e0; base < e1; base += 8) {
                    int a[8];
#pragma unroll
                    for (int u = 0; u < 8; ++u) {
                        int ee = base + u;
                        a[u] = adj[ee < e1 ? ee : e1 - 1];  // dupes max-neutral
                    }
                    float4 v[8];
#pragma unroll
                    for (int u = 0; u < 8; ++u) v[u] = X4[(size_t)a[u] * 32 + f4];
#pragma unroll
                    for (int u = 0; u < 8; ++u) {
                        acc[u].x = fmaxf(acc[u].x, v[u].x);
                        acc[u].y = fmaxf(acc[u].y, v[u].y);
                        acc[u].z = fmaxf(acc[u].z, v[u].z);
                        acc[u].w = fmaxf(acc[u].w, v[u].w);
                    }
                }
#pragma unroll
                for (int u = 4; u < 8; ++u) {
                    acc[u - 4].x = fmaxf(acc[u - 4].x, acc[u].x);
                    acc[u - 4].y = fmaxf(acc[u - 4].y, acc[u].y);
                    acc[u - 4].z = fmaxf(acc[u - 4].z, acc[u].z);
                    acc[u - 4].w = fmaxf(acc[u - 4].w, acc[u].w);
                }
                b.x = fmaxf(fmaxf(acc[0].x, acc[1].x), fmaxf(acc[2].x, acc[3].x));
                b.y = fmaxf(fmaxf(acc[0].y, acc[1].y), fmaxf(acc[2].y, acc[3].y));
                b.z = fmaxf(fmaxf(acc[0].z, acc[1].z), fmaxf(acc[2].z, acc[3].z));
                b.w = fmaxf(fmaxf(acc[0].w, acc[1].w), fmaxf(acc[2].w, acc[3].w));
            }
            // split + swizzled image write (full-K image, row stride 128)
            float f[4] = {b.x, b.y, b.z, b.w};
            half4 h, l;
#pragma unroll
            for (int j = 0; j < 4; ++j) {
                _Float16 hh = (_Float16)f[j];
                h[j] = hh;
                l[j] = (_Float16)(f[j] - (float)hh);
            }
            int g16 = f4 >> 1;
            int pos = (g16 & 8) | ((g16 & 7) ^ (row & 7));
            int off = row * 128 + pos * 8 + (f4 & 1) * 4;
            *(half4*)&sU[off] = h;
            *(half4*)&sU[8192 + off] = l;
        }
    }
    __syncthreads();

    f32x16 acc[2];
#pragma unroll
    for (int nt = 0; nt < 2; ++nt) {
        float bv = bias[wc * 64 + nt * 32 + l31];
#pragma unroll
        for (int r = 0; r < 16; ++r) acc[nt][r] = bv;
    }

    int rl = ws * 32 + l31;  // this lane's A row within the tile

    // ---- Pass 0: m @ Wl^T (A from full-K sU image) ----
    for (int kc = 0; kc < 2; ++kc) {
        if (kc) __syncthreads();  // prior chunk's sB reads done
        {
            const half8* bsrc = (const half8*)(Bimg + (size_t)kc * 16384);
            half8* bdst = (half8*)sB;
#pragma unroll
            for (int i = 0; i < 8; ++i) bdst[tid + i * 256] = bsrc[tid + i * 256];
        }
        __syncthreads();
#pragma unroll
        for (int ks = 0; ks < 4; ++ks) {
            int gp = ks * 2 + lhi;
            int posA = kc * 8 + (gp ^ (rl & 7));
            half8 ah = *(const half8*)&sU[rl * 128 + posA * 8];
            half8 al = *(const half8*)&sU[8192 + rl * 128 + posA * 8];
#pragma unroll
            for (int nt = 0; nt < 2; ++nt) {
                int n = wc * 64 + nt * 32 + l31;
                int posB = gp ^ (n & 7);
                half8 bh = *(const half8*)&sB[n * 64 + posB * 8];
                half8 bl = *(const half8*)&sB[8192 + n * 64 + posB * 8];
                acc[nt] = __builtin_amdgcn_mfma_f32_32x32x16_f16(ah, bh, acc[nt], 0, 0, 0);
                acc[nt] = __builtin_amdgcn_mfma_f32_32x32x16_f16(al, bh, acc[nt], 0, 0, 0);
                acc[nt] = __builtin_amdgcn_mfma_f32_32x32x16_f16(ah, bl, acc[nt], 0, 0, 0);
            }
        }
    }

    // ---- Pass 1: x @ Wr^T (x chunks staged into sU's first 16 KB) ----
    for (int kc = 0; kc < 2; ++kc) {
        __syncthreads();  // prior readers of sU/sB done
        {
            const half8* bsrc = (const half8*)(Bimg + 32768 + (size_t)kc * 16384);
            half8* bdst = (half8*)sB;
#pragma unroll
            for (int i = 0; i < 8; ++i) bdst[tid + i * 256] = bsrc[tid + i * 256];
        }
#pragma unroll
        for (int i = 0; i < 4; ++i) {
            int idx = tid + i * 256;  // [0,1024)
            int row = idx >> 4;       // [0,64)
            int f4l = idx & 15;
            int n = n0 + row;
            float4 v = make_float4(0.f, 0.f, 0.f, 0.f);
            if (n < N) v = X4[(size_t)n * 32 + kc * 16 + f4l];
            float f[4] = {v.x, v.y, v.z, v.w};
            half4 h, l;
#pragma unroll
            for (int j = 0; j < 4; ++j) {
                _Float16 hh = (_Float16)f[j];
                h[j] = hh;
                l[j] = (_Float16)(f[j] - (float)hh);
            }
            int gp = f4l >> 1;
            int pos = gp ^ (row & 7);
            int off = row * 64 + pos * 8 + (f4l & 1) * 4;
            *(half4*)&sU[off] = h;
            *(half4*)&sU[4096 + off] = l;
        }
        __syncthreads();
#pragma unroll
        for (int ks = 0; ks < 4; ++ks) {
            int gp = ks * 2 + lhi;
            int posA = gp ^ (rl & 7);
            half8 ah = *(const half8*)&sU[rl * 64 + posA * 8];
            half8 al = *(const half8*)&sU[4096 + rl * 64 + posA * 8];
#pragma unroll
            for (int nt = 0; nt < 2; ++nt) {
                int n = wc * 64 + nt * 32 + l31;
                int posB = gp ^ (n & 7);
                half8 bh = *(const half8*)&sB[n * 64 + posB * 8];
                half8 bl = *(const half8*)&sB[8192 + n * 64 + posB * 8];
                acc[nt] = __builtin_amdgcn_mfma_f32_32x32x16_f16(ah, bh, acc[nt], 0, 0, 0);
                acc[nt] = __builtin_amdgcn_mfma_f32_32x32x16_f16(al, bh, acc[nt], 0, 0, 0);
                acc[nt] = __builtin_amdgcn_mfma_f32_32x32x16_f16(ah, bl, acc[nt], 0, 0, 0);
            }
        }
    }

    // epilogue: relu + store. C/D: col=l31(+base), row=(r&3)+8*(r>>2)+4*lhi
#pragma unroll
    for (int r = 0; r < 16; ++r) {
        int row = n0 + ws * 32 + (r & 3) + 8 * (r >> 2) + 4 * lhi;
        if (row < N) {
#pragma unroll
            for (int nt = 0; nt < 2; ++nt) {
                int col = wc * 64 + nt * 32 + l31;
                xout[(size_t)row * H + col] = fmaxf(acc[nt][r], 0.f);
            }
        }
    }
}

// ---------------- MFMA final linear + cosine, LDS-staged, K-chunked --------
// Block 256 = 4 waves; each wave an independent 32-row stripe x 128 cols
// (nt=4) so the cosine reduction stays within 32 lanes. 128 rows/block.

__global__ __launch_bounds__(256) void final_mfma4(
    const float* __restrict__ xin, const _Float16* __restrict__ Bimg,  // Wlin
    const float* __restrict__ blin, const float* __restrict__ qn,
    const int* __restrict__ bv, float* __restrict__ out, int N) {
    __shared__ __align__(16) _Float16 sA[2][8192];  // [hl][row*64 + pos*8], 128 rows
    __shared__ __align__(16) _Float16 sB[2][8192];  // [hl][n*64 + pos*8], 128 cols

    int tid = threadIdx.x;
    int w = tid >> 6;
    int lane = tid & 63;
    int l31 = lane & 31;
    int lhi = lane >> 5;
    int n0 = blockIdx.x * 128;

    int arow = n0 + w * 32 + l31;
    arow = arow < N ? arow : N - 1;
    int gl = bv[arow];  // stripe's graph ids, indexed by l31

    f32x16 acc[4];
#pragma unroll
    for (int nt = 0; nt < 4; ++nt) {
        float b = blin[nt * 32 + l31];
#pragma unroll
        for (int r = 0; r < 16; ++r) acc[nt][r] = b;
    }

    int rl = w * 32 + l31;
    const float4* A4 = (const float4*)xin;

    for (int kc = 0; kc < 2; ++kc) {
        __syncthreads();
        {
            const half8* bsrc = (const half8*)(Bimg + (size_t)kc * 16384);
            half8* bdst = (half8*)&sB[0][0];
#pragma unroll
            for (int i = 0; i < 8; ++i) bdst[tid + i * 256] = bsrc[tid + i * 256];
        }
#pragma unroll
        for (int i = 0; i < 8; ++i) {
            int idx = tid + i * 256;  // [0,2048)
            int row = idx >> 4;       // [0,128)
            int f4l = idx & 15;
            int n = n0 + row;
            float4 v = make_float4(0.f, 0.f, 0.f, 0.f);
            if (n < N) v = A4[(size_t)n * 32 + kc * 16 + f4l];
            float f[4] = {v.x, v.y, v.z, v.w};
            half4 h, l;
#pragma unroll
            for (int j = 0; j < 4; ++j) {
                _Float16 hh = (_Float16)f[j];
                h[j] = hh;
                l[j] = (_Float16)(f[j] - (float)hh);
            }
            int gp = f4l >> 1;
            int pos = gp ^ (row & 7);
            int off = row * 64 + pos * 8 + (f4l & 1) * 4;
            *(half4*)&sA[0][off] = h;
            *(half4*)&sA[1][off] = l;
        }
        __syncthreads();

#pragma unroll
        for (int ks = 0; ks < 4; ++ks) {
            int gp = ks * 2 + lhi;
            int posA = gp ^ (rl & 7);
            half8 ah = *(const half8*)&sA[0][rl * 64 + posA * 8];
            half8 al = *(const half8*)&sA[1][rl * 64 + posA * 8];
#pragma unroll
            for (int nt = 0; nt < 4; ++nt) {
                int n = nt * 32 + l31;
                int posB = gp ^ (n & 7);
                half8 bh = *(const half8*)&sB[0][n * 64 + posB * 8];
                half8 bl = *(const half8*)&sB[1][n * 64 + posB * 8];
                acc[nt] = __builtin_amdgcn_mfma_f32_32x32x16_f16(ah, bh, acc[nt], 0, 0, 0);
                acc[nt] = __builtin_amdgcn_mfma_f32_32x32x16_f16(al, bh, acc[nt], 0, 0, 0);
                acc[nt] = __builtin_amdgcn_mfma_f32_32x32x16_f16(ah, bl, acc[nt], 0, 0, 0);
            }
        }
    }

    // cosine epilogue: row rloc owned by 32 lanes (l31); xor<=16 stays in group
#pragma unroll
    for (int r = 0; r < 16; ++r) {
        int rloc = (r & 3) + 8 * (r >> 2) + 4 * lhi;
        int row = n0 + w * 32 + rloc;
        int g = __shfl(gl, rloc, 32);  // stripe-row rloc's graph id
        float ss = 0.f, sd = 0.f;
#pragma unroll
        for (int nt = 0; nt < 4; ++nt) {
            float y = acc[nt][r];
            float q = qn[(size_t)g * H + nt * 32 + l31];
            ss = fmaf(y, y, ss);
            sd = fmaf(y, q, sd);
        }
#pragma unroll
        for (int off = 1; off <= 16; off <<= 1) {
            ss += __shfl_xor(ss, off, 64);
            sd += __shfl_xor(sd, off, 64);
        }
        if (l31 == 0 && row < N) out[row] = sd / fmaxf(sqrtf(ss), 1e-12f);
    }
}

// ---------------- launch ----------------

extern "C" void kernel_launch(void* const* d_in, const int* in_sizes, int n_in,
                              void* d_out, int out_size, void* d_ws, size_t ws_size,
                              hipStream_t stream) {
    const float* x = (const float*)d_in[0];
    const float* query = (const float*)d_in[1];
    const float* Wl = (const float*)d_in[2];
    const float* bl = (const float*)d_in[3];
    const float* Wr = (const float*)d_in[4];
    const float* Wlin = (const float*)d_in[5];
    const float* blin = (const float*)d_in[6];
    const int* ei = (const int*)d_in[7];
    const int* bv = (const int*)d_in[8];
    float* out = (float*)d_out;

    const int N = in_sizes[0] / H;
    const int E = in_sizes[7] / 2;
    const int G = in_sizes[1] / H;
    const int NB = (N + 255) / 256;

    char* p = (char*)d_ws;
    auto alloc = [&](size_t bytes) {
        char* r = p;
        p += (bytes + 255) & ~(size_t)255;
        return r;
    };
    int* deg = (int*)alloc((size_t)2 * N * sizeof(int));  // deg then cursor
    int* cursor = deg + N;
    int* offsets = (int*)alloc((size_t)(N + 1) * sizeof(int));
    int* bsum = (int*)alloc((size_t)NB * sizeof(int));
    int* bbase = (int*)alloc((size_t)NB * sizeof(int));
    int* adj = (int*)alloc((size_t)E * sizeof(int));
    float* qn = (float*)alloc((size_t)G * H * sizeof(float));
    _Float16* wimg = (_Float16*)alloc((size_t)7 * 32768 * sizeof(_Float16));
    float* xb0 = (float*)alloc((size_t)N * H * sizeof(float));
    float* xb1 = (float*)alloc((size_t)N * H * sizeof(float));

    zero_ints<<<(2 * N + 255) / 256, 256, 0, stream>>>(deg, 2 * N);
    hist_deg<<<(E + 255) / 256, 256, 0, stream>>>(ei, E, deg);
    block_sums<<<NB, 256, 0, stream>>>(deg, bsum, N);
    scan_bsum<<<1, 64, 0, stream>>>(bsum, bbase, NB, offsets + N);
    scan_within<<<NB, 256, 0, stream>>>(deg, bbase, offsets, N);
    fill_adj<<<(E + 255) / 256, 256, 0, stream>>>(ei, E, offsets, cursor, adj);
    prep_query<<<G, 128, 0, stream>>>(query, qn);
    prep_wsplit<<<(7 * 2048 + 255) / 256, 256, 0, stream>>>(Wl, Wr, Wlin, wimg);

    const int NGm = (N + 63) / 64;    // fused layer blocks
    const int NGf = (N + 127) / 128;  // final blocks

    layer_fused<<<NGm, 256, 0, stream>>>(x, offsets, adj, wimg + (size_t)0 * 65536,
                                         bl + 0 * H, xb0, N);
    layer_fused<<<NGm, 256, 0, stream>>>(xb0, offsets, adj, wimg + (size_t)1 * 65536,
                                         bl + 1 * H, xb1, N);
    layer_fused<<<NGm, 256, 0, stream>>>(xb1, offsets, adj, wimg + (size_t)2 * 65536,
                                         bl + 2 * H, xb0, N);
    final_mfma4<<<NGf, 256, 0, stream>>>(xb0, wimg + (size_t)6 * 32768, blin, qn,
                                         bv, out, N);
}

// Round 9
// 334.184 us; speedup vs baseline: 1.1757x; 1.1757x over previous
//
#include <hip/hip_runtime.h>
#include <math.h>

#define H 128

typedef _Float16 half8 __attribute__((ext_vector_type(8)));
typedef _Float16 half4 __attribute__((ext_vector_type(4)));
typedef float f32x16 __attribute__((ext_vector_type(16)));

// ---------------- CSR build ----------------

__global__ __launch_bounds__(256) void hist_deg(const int* __restrict__ ei, int E,
                                                int* __restrict__ deg) {
    int e = blockIdx.x * 256 + threadIdx.x;
    if (e < E) atomicAdd(&deg[ei[E + e]], 1);  // dst row of edge_index
}

__global__ __launch_bounds__(256) void block_sums(const int* __restrict__ deg,
                                                  int* __restrict__ bsum, int N) {
    __shared__ int part[4];
    int tid = threadIdx.x;
    int i = blockIdx.x * 256 + tid;
    int v = (i < N) ? deg[i] : 0;
#pragma unroll
    for (int off = 32; off > 0; off >>= 1) v += __shfl_down(v, off, 64);
    if ((tid & 63) == 0) part[tid >> 6] = v;
    __syncthreads();
    if (tid == 0) bsum[blockIdx.x] = part[0] + part[1] + part[2] + part[3];
}

__global__ __launch_bounds__(64) void scan_bsum(const int* __restrict__ bsum,
                                                int* __restrict__ bbase, int NB,
                                                int* __restrict__ totalOut) {
    int lane = threadIdx.x;
    int base = 0;
    for (int s0 = 0; s0 < NB; s0 += 64) {
        int i = s0 + lane;
        int v = (i < NB) ? bsum[i] : 0;
        int incl = v;
#pragma unroll
        for (int off = 1; off < 64; off <<= 1) {
            int t = __shfl_up(incl, off, 64);
            if (lane >= off) incl += t;
        }
        if (i < NB) bbase[i] = base + incl - v;
        base += __shfl(incl, 63, 64);
    }
    if (lane == 0) *totalOut = base;  // offsets[N] = E
}

__global__ __launch_bounds__(256) void scan_within(const int* __restrict__ deg,
                                                   const int* __restrict__ bbase,
                                                   int* __restrict__ offsets, int N) {
    __shared__ int buf[256];
    int tid = threadIdx.x;
    int i = blockIdx.x * 256 + tid;
    int v = (i < N) ? deg[i] : 0;
    int incl = v;
    buf[tid] = v;
    __syncthreads();
#pragma unroll
    for (int off = 1; off < 256; off <<= 1) {
        int t = (tid >= off) ? buf[tid - off] : 0;
        __syncthreads();
        incl += t;
        buf[tid] = incl;
        __syncthreads();
    }
    if (i < N) offsets[i] = bbase[blockIdx.x] + incl - v;  // exclusive scan
}

__global__ __launch_bounds__(256) void fill_adj(const int* __restrict__ ei, int E,
                                                const int* __restrict__ offsets,
                                                int* __restrict__ cursor,
                                                int* __restrict__ adj) {
    int e = blockIdx.x * 256 + threadIdx.x;
    if (e < E) {
        int s = ei[e];
        int d = ei[E + e];
        int pos = atomicAdd(&cursor[d], 1);
        adj[offsets[d] + pos] = s;
    }
}

// ---------------- query normalization ----------------

__global__ __launch_bounds__(128) void prep_query(const float* __restrict__ query,
                                                  float* __restrict__ qn) {
    int g = blockIdx.x;
    int f = threadIdx.x;
    float v = query[g * H + f];
    float ss = v * v;
#pragma unroll
    for (int off = 32; off > 0; off >>= 1) ss += __shfl_xor(ss, off, 64);
    __shared__ float part[2];
    if ((f & 63) == 0) part[f >> 6] = ss;
    __syncthreads();
    float tot = part[0] + part[1];
    qn[g * H + f] = v / fmaxf(sqrtf(tot), 1e-12f);
}

// ---------------- weight split into swizzled, K-chunked LDS images ----------
// mat order: Wl0,Wr0,Wl1,Wr1,Wl2,Wr2,Wlin. Address of (mat, kc, hl):
//   mat*32768 + kc*16384 + hl*8192 halves.
// Chunk image: [n][pos*8], pos = gp ^ (n&7), gp = granule within chunk.

__global__ __launch_bounds__(256) void prep_wsplit(const float* __restrict__ Wl,
                                                   const float* __restrict__ Wr,
                                                   const float* __restrict__ Wlin,
                                                   _Float16* __restrict__ img) {
    int gidx = blockIdx.x * 256 + threadIdx.x;
    if (gidx >= 7 * 128 * 16) return;
    int mat = gidx / 2048;
    int rem = gidx - mat * 2048;
    int n = rem >> 4;
    int g = rem & 15;  // global granule [0,16)
    const float* src = (mat == 6) ? Wlin
                     : ((mat & 1) ? Wr + (mat >> 1) * H * H : Wl + (mat >> 1) * H * H);
    const float* p = src + n * H + g * 8;
    half8 h, l;
#pragma unroll
    for (int j = 0; j < 8; ++j) {
        float v = p[j];
        _Float16 hh = (_Float16)v;
        h[j] = hh;
        l[j] = (_Float16)(v - (float)hh);
    }
    int kc = g >> 3, gp = g & 7;
    int pos = gp ^ (n & 7);
    size_t cbase = (((size_t)mat * 2 + kc) * 2) * 8192 + (size_t)n * 64 + pos * 8;
    *(half8*)(img + cbase) = h;         // hi
    *(half8*)(img + cbase + 8192) = l;  // lo
}

// ---------------- initial activation split ----------------

__global__ __launch_bounds__(256) void split_x(const float4* __restrict__ x4,
                                               half8* __restrict__ xh,
                                               half8* __restrict__ xl, int n8) {
    int i = blockIdx.x * 256 + threadIdx.x;
    if (i >= n8) return;
    float4 u = x4[(size_t)i * 2], v = x4[(size_t)i * 2 + 1];
    float f[8] = {u.x, u.y, u.z, u.w, v.x, v.y, v.z, v.w};
    half8 h, l;
#pragma unroll
    for (int j = 0; j < 8; ++j) {
        _Float16 hh = (_Float16)f[j];
        h[j] = hh;
        l[j] = (_Float16)(f[j] - (float)hh);
    }
    xh[i] = h;
    xl[i] = l;
}

// ---------------- fused layer: hi-gather-max + dual GEMM + bias + relu -----
// Y = relu(segmax(X) @ Wl^T + bias + X @ Wr^T).
// X held as split fp16 (Xh, Xl). Gather reads ONLY Xh (monotone RN16:
// max of hi == hi of max), so m is fp16-exact -> m_lo == 0 -> pass 0 uses
// 2 MFMAs (ah*bh + ah*bl); pass 1 (x@Wr) keeps full split precision (3).
// Block 256 = 4 waves; tile 64 rows x 128 cols.
// LDS: sU 16 KB (m image / x chunk) + sB 32 KB = 48 KB -> 3 blocks/CU.

__global__ __launch_bounds__(256) void layer_fused(
    const half8* __restrict__ Xh, const half8* __restrict__ Xl,
    const int* __restrict__ offsets, const int* __restrict__ adj,
    const _Float16* __restrict__ Bimg, const float* __restrict__ bias,
    _Float16* __restrict__ Yh, _Float16* __restrict__ Yl, int N) {
    __shared__ __align__(16) _Float16 sU[8192];   // m image (full K) / x chunk
    __shared__ __align__(16) _Float16 sB[16384];  // B chunk hi/lo

    int tid = threadIdx.x;
    int w = tid >> 6;
    int lane = tid & 63;
    int l31 = lane & 31;
    int lhi = lane >> 5;
    int ws = w >> 1;  // row stripe (32 rows)
    int wc = w & 1;   // col half (64 cols)
    int n0 = blockIdx.x * 64;

    // ---- Phase G: hi-only gather segment-max for rows n0..n0+63 ----
    // 16 lanes per node (half8 each = 256 B row), 16 groups x 4 nodes.
    {
        int lf = tid & 15;
        int grp = tid >> 4;
        for (int i = 0; i < 4; ++i) {
            int row = grp * 4 + i;
            int node = n0 + row;
            int nc = node < N ? node : N - 1;
            int e0 = offsets[nc], e1 = offsets[nc + 1];
            float best[8];
#pragma unroll
            for (int j = 0; j < 8; ++j) best[j] = 0.f;
            if (node < N && e1 > e0) {
                float acc[4][8];
#pragma unroll
                for (int u = 0; u < 4; ++u)
#pragma unroll
                    for (int j = 0; j < 8; ++j) acc[u][j] = -INFINITY;
                for (int base = e0; base < e1; base += 4) {
                    int a[4];
#pragma unroll
                    for (int u = 0; u < 4; ++u) {
                        int ee = base + u;
                        a[u] = adj[ee < e1 ? ee : e1 - 1];  // dupes max-neutral
                    }
                    half8 v[4];
#pragma unroll
                    for (int u = 0; u < 4; ++u) v[u] = Xh[(size_t)a[u] * 16 + lf];
#pragma unroll
                    for (int u = 0; u < 4; ++u)
#pragma unroll
                        for (int j = 0; j < 8; ++j)
                            acc[u][j] = fmaxf(acc[u][j], (float)v[u][j]);
                }
#pragma unroll
                for (int j = 0; j < 8; ++j)
                    best[j] = fmaxf(fmaxf(acc[0][j], acc[1][j]),
                                    fmaxf(acc[2][j], acc[3][j]));
            }
            half8 hv;
#pragma unroll
            for (int j = 0; j < 8; ++j) hv[j] = (_Float16)best[j];  // exact
            int pos = (lf & 8) | ((lf & 7) ^ (row & 7));
            *(half8*)&sU[row * 128 + pos * 8] = hv;
        }
    }
    __syncthreads();

    f32x16 acc[2];
#pragma unroll
    for (int nt = 0; nt < 2; ++nt) {
        float bv = bias[wc * 64 + nt * 32 + l31];
#pragma unroll
        for (int r = 0; r < 16; ++r) acc[nt][r] = bv;
    }

    int rl = ws * 32 + l31;  // this lane's A row within the tile

    // ---- Pass 0: m @ Wl^T (A = fp16-exact m image; 2 MFMAs) ----
    for (int kc = 0; kc < 2; ++kc) {
        if (kc) __syncthreads();
        {
            const half8* bsrc = (const half8*)(Bimg + (size_t)kc * 16384);
            half8* bdst = (half8*)sB;
#pragma unroll
            for (int i = 0; i < 8; ++i) bdst[tid + i * 256] = bsrc[tid + i * 256];
        }
        __syncthreads();
#pragma unroll
        for (int ks = 0; ks < 4; ++ks) {
            int gp = ks * 2 + lhi;
            int posA = kc * 8 + (gp ^ (rl & 7));
            half8 ah = *(const half8*)&sU[rl * 128 + posA * 8];
#pragma unroll
            for (int nt = 0; nt < 2; ++nt) {
                int n = wc * 64 + nt * 32 + l31;
                int posB = gp ^ (n & 7);
                half8 bh = *(const half8*)&sB[n * 64 + posB * 8];
                half8 bl = *(const half8*)&sB[8192 + n * 64 + posB * 8];
                acc[nt] = __builtin_amdgcn_mfma_f32_32x32x16_f16(ah, bh, acc[nt], 0, 0, 0);
                acc[nt] = __builtin_amdgcn_mfma_f32_32x32x16_f16(ah, bl, acc[nt], 0, 0, 0);
            }
        }
    }

    // ---- Pass 1: x @ Wr^T (x chunks copied pre-split from Xh/Xl; 3 MFMAs) --
    for (int kc = 0; kc < 2; ++kc) {
        __syncthreads();
        {
            const half8* bsrc = (const half8*)(Bimg + 32768 + (size_t)kc * 16384);
            half8* bdst = (half8*)sB;
#pragma unroll
            for (int i = 0; i < 8; ++i) bdst[tid + i * 256] = bsrc[tid + i * 256];
        }
        // stage x chunk: straight swizzled copy, no split VALU
#pragma unroll
        for (int i = 0; i < 2; ++i) {
            int idx = tid + i * 256;  // [0,512)
            int row = idx >> 3;       // [0,64)
            int gp = idx & 7;
            int n = n0 + row;
            half8 h = {0, 0, 0, 0, 0, 0, 0, 0}, l = {0, 0, 0, 0, 0, 0, 0, 0};
            if (n < N) {
                h = Xh[(size_t)n * 16 + kc * 8 + gp];
                l = Xl[(size_t)n * 16 + kc * 8 + gp];
            }
            int pos = gp ^ (row & 7);
            *(half8*)&sU[row * 64 + pos * 8] = h;
            *(half8*)&sU[4096 + row * 64 + pos * 8] = l;
        }
        __syncthreads();
#pragma unroll
        for (int ks = 0; ks < 4; ++ks) {
            int gp = ks * 2 + lhi;
            int posA = gp ^ (rl & 7);
            half8 ah = *(const half8*)&sU[rl * 64 + posA * 8];
            half8 al = *(const half8*)&sU[4096 + rl * 64 + posA * 8];
#pragma unroll
            for (int nt = 0; nt < 2; ++nt) {
                int n = wc * 64 + nt * 32 + l31;
                int posB = gp ^ (n & 7);
                half8 bh = *(const half8*)&sB[n * 64 + posB * 8];
                half8 bl = *(const half8*)&sB[8192 + n * 64 + posB * 8];
                acc[nt] = __builtin_amdgcn_mfma_f32_32x32x16_f16(ah, bh, acc[nt], 0, 0, 0);
                acc[nt] = __builtin_amdgcn_mfma_f32_32x32x16_f16(al, bh, acc[nt], 0, 0, 0);
                acc[nt] = __builtin_amdgcn_mfma_f32_32x32x16_f16(ah, bl, acc[nt], 0, 0, 0);
            }
        }
    }

    // epilogue: relu + split store. C/D: col=l31(+base), row=(r&3)+8*(r>>2)+4*lhi
#pragma unroll
    for (int r = 0; r < 16; ++r) {
        int row = n0 + ws * 32 + (r & 3) + 8 * (r >> 2) + 4 * lhi;
        if (row < N) {
#pragma unroll
            for (int nt = 0; nt < 2; ++nt) {
                int col = wc * 64 + nt * 32 + l31;
                float y = fmaxf(acc[nt][r], 0.f);
                _Float16 h = (_Float16)y;
                Yh[(size_t)row * H + col] = h;
                Yl[(size_t)row * H + col] = (_Float16)(y - (float)h);
            }
        }
    }
}

// ---------------- MFMA final linear + cosine, split-fp16 A ----------------
// Block 256 = 4 waves; each wave an independent 32-row stripe x 128 cols
// (nt=4) so the cosine reduction stays within 32 lanes. 128 rows/block.
// LDS: sA 32 KB + sB 32 KB = 64 KB. A staged by straight swizzled copy.

__global__ __launch_bounds__(256) void final_mfma5(
    const half8* __restrict__ Xh, const half8* __restrict__ Xl,
    const _Float16* __restrict__ Bimg,  // Wlin chunked images
    const float* __restrict__ blin, const float* __restrict__ qn,
    const int* __restrict__ bv, float* __restrict__ out, int N) {
    __shared__ __align__(16) _Float16 sA[2][8192];  // [hl][row*64 + pos*8]
    __shared__ __align__(16) _Float16 sB[2][8192];

    int tid = threadIdx.x;
    int w = tid >> 6;
    int lane = tid & 63;
    int l31 = lane & 31;
    int lhi = lane >> 5;
    int n0 = blockIdx.x * 128;

    int arow = n0 + w * 32 + l31;
    arow = arow < N ? arow : N - 1;
    int gl = bv[arow];  // stripe's graph ids, indexed by l31

    f32x16 acc[4];
#pragma unroll
    for (int nt = 0; nt < 4; ++nt) {
        float b = blin[nt * 32 + l31];
#pragma unroll
        for (int r = 0; r < 16; ++r) acc[nt][r] = b;
    }

    int rl = w * 32 + l31;

    for (int kc = 0; kc < 2; ++kc) {
        __syncthreads();
        {
            const half8* bsrc = (const half8*)(Bimg + (size_t)kc * 16384);
            half8* bdst = (half8*)&sB[0][0];
#pragma unroll
            for (int i = 0; i < 8; ++i) bdst[tid + i * 256] = bsrc[tid + i * 256];
        }
        // stage A chunk: 128 rows x 8 granules, hi+lo straight swizzled copy
#pragma unroll
        for (int i = 0; i < 4; ++i) {
            int idx = tid + i * 256;  // [0,1024)
            int row = idx >> 3;       // [0,128)
            int gp = idx & 7;
            int n = n0 + row;
            half8 h = {0, 0, 0, 0, 0, 0, 0, 0}, l = {0, 0, 0, 0, 0, 0, 0, 0};
            if (n < N) {
                h = Xh[(size_t)n * 16 + kc * 8 + gp];
                l = Xl[(size_t)n * 16 + kc * 8 + gp];
            }
            int pos = gp ^ (row & 7);
            *(half8*)&sA[0][row * 64 + pos * 8] = h;
            *(half8*)&sA[1][row * 64 + pos * 8] = l;
        }
        __syncthreads();

#pragma unroll
        for (int ks = 0; ks < 4; ++ks) {
            int gp = ks * 2 + lhi;
            int posA = gp ^ (rl & 7);
            half8 ah = *(const half8*)&sA[0][rl * 64 + posA * 8];
            half8 al = *(const half8*)&sA[1][rl * 64 + posA * 8];
#pragma unroll
            for (int nt = 0; nt < 4; ++nt) {
                int n = nt * 32 + l31;
                int posB = gp ^ (n & 7);
                half8 bh = *(const half8*)&sB[0][n * 64 + posB * 8];
                half8 bl = *(const half8*)&sB[1][n * 64 + posB * 8];
                acc[nt] = __builtin_amdgcn_mfma_f32_32x32x16_f16(ah, bh, acc[nt], 0, 0, 0);
                acc[nt] = __builtin_amdgcn_mfma_f32_32x32x16_f16(al, bh, acc[nt], 0, 0, 0);
                acc[nt] = __builtin_amdgcn_mfma_f32_32x32x16_f16(ah, bl, acc[nt], 0, 0, 0);
            }
        }
    }

    // cosine epilogue: row rloc owned by 32 lanes (l31); xor<=16 stays in group
#pragma unroll
    for (int r = 0; r < 16; ++r) {
        int rloc = (r & 3) + 8 * (r >> 2) + 4 * lhi;
        int row = n0 + w * 32 + rloc;
        int g = __shfl(gl, rloc, 32);  // stripe-row rloc's graph id
        float ss = 0.f, sd = 0.f;
#pragma unroll
        for (int nt = 0; nt < 4; ++nt) {
            float y = acc[nt][r];
            float q = qn[(size_t)g * H + nt * 32 + l31];
            ss = fmaf(y, y, ss);
            sd = fmaf(y, q, sd);
        }
#pragma unroll
        for (int off = 1; off <= 16; off <<= 1) {
            ss += __shfl_xor(ss, off, 64);
            sd += __shfl_xor(sd, off, 64);
        }
        if (l31 == 0 && row < N) out[row] = sd / fmaxf(sqrtf(ss), 1e-12f);
    }
}

// ---------------- launch ----------------

extern "C" void kernel_launch(void* const* d_in, const int* in_sizes, int n_in,
                              void* d_out, int out_size, void* d_ws, size_t ws_size,
                              hipStream_t stream) {
    const float* x = (const float*)d_in[0];
    const float* query = (const float*)d_in[1];
    const float* Wl = (const float*)d_in[2];
    const float* bl = (const float*)d_in[3];
    const float* Wr = (const float*)d_in[4];
    const float* Wlin = (const float*)d_in[5];
    const float* blin = (const float*)d_in[6];
    const int* ei = (const int*)d_in[7];
    const int* bv = (const int*)d_in[8];
    float* out = (float*)d_out;

    const int N = in_sizes[0] / H;
    const int E = in_sizes[7] / 2;
    const int G = in_sizes[1] / H;
    const int NB = (N + 255) / 256;

    char* p = (char*)d_ws;
    auto alloc = [&](size_t bytes) {
        char* r = p;
        p += (bytes + 255) & ~(size_t)255;
        return r;
    };
    int* deg = (int*)alloc((size_t)2 * N * sizeof(int));  // deg then cursor
    int* cursor = deg + N;
    int* offsets = (int*)alloc((size_t)(N + 1) * sizeof(int));
    int* bsum = (int*)alloc((size_t)NB * sizeof(int));
    int* bbase = (int*)alloc((size_t)NB * sizeof(int));
    int* adj = (int*)alloc((size_t)E * sizeof(int));
    float* qn = (float*)alloc((size_t)G * H * sizeof(float));
    _Float16* wimg = (_Float16*)alloc((size_t)7 * 32768 * sizeof(_Float16));
    size_t actH = (size_t)N * H * sizeof(_Float16);
    _Float16* xah = (_Float16*)alloc(actH);
    _Float16* xal = (_Float16*)alloc(actH);
    _Float16* xbh = (_Float16*)alloc(actH);
    _Float16* xbl = (_Float16*)alloc(actH);

    hipMemsetAsync(deg, 0, (size_t)2 * N * sizeof(int), stream);
    hist_deg<<<(E + 255) / 256, 256, 0, stream>>>(ei, E, deg);
    block_sums<<<NB, 256, 0, stream>>>(deg, bsum, N);
    scan_bsum<<<1, 64, 0, stream>>>(bsum, bbase, NB, offsets + N);
    scan_within<<<NB, 256, 0, stream>>>(deg, bbase, offsets, N);
    fill_adj<<<(E + 255) / 256, 256, 0, stream>>>(ei, E, offsets, cursor, adj);
    prep_query<<<G, 128, 0, stream>>>(query, qn);
    prep_wsplit<<<(7 * 2048 + 255) / 256, 256, 0, stream>>>(Wl, Wr, Wlin, wimg);

    const int n8 = N * H / 8;
    split_x<<<(n8 + 255) / 256, 256, 0, stream>>>((const float4*)x, (half8*)xah,
                                                  (half8*)xal, n8);

    const int NGm = (N + 63) / 64;    // fused layer blocks
    const int NGf = (N + 127) / 128;  // final blocks

    layer_fused<<<NGm, 256, 0, stream>>>(
        (const half8*)xah, (const half8*)xal, offsets, adj,
        wimg + (size_t)0 * 65536, bl + 0 * H, xbh, xbl, N);
    layer_fused<<<NGm, 256, 0, stream>>>(
        (const half8*)xbh, (const half8*)xbl, offsets, adj,
        wimg + (size_t)1 * 65536, bl + 1 * H, xah, xal, N);
    layer_fused<<<NGm, 256, 0, stream>>>(
        (const half8*)xah, (const half8*)xal, offsets, adj,
        wimg + (size_t)2 * 65536, bl + 2 * H, xbh, xbl, N);
    final_mfma5<<<NGf, 256, 0, stream>>>(
        (const half8*)xbh, (const half8*)xbl, wimg + (size_t)6 * 32768, blin, qn,
        bv, out, N);
}

// Round 10
// 285.121 us; speedup vs baseline: 1.3780x; 1.1721x over previous
//
#include <hip/hip_runtime.h>
#include <math.h>

#define H 128

typedef _Float16 half8 __attribute__((ext_vector_type(8)));
typedef float f32x16 __attribute__((ext_vector_type(16)));

__device__ __forceinline__ half8 h8max(half8 a, half8 b) {
#if defined(__has_builtin) && __has_builtin(__builtin_elementwise_max)
    return __builtin_elementwise_max(a, b);
#else
    half8 r;
#pragma unroll
    for (int j = 0; j < 8; ++j) r[j] = a[j] > b[j] ? a[j] : b[j];
    return r;
#endif
}

// ---------------- CSR build ----------------

__global__ __launch_bounds__(256) void hist_deg(const int* __restrict__ ei, int E,
                                                int* __restrict__ deg) {
    int e = blockIdx.x * 256 + threadIdx.x;
    if (e < E) atomicAdd(&deg[ei[E + e]], 1);  // dst row of edge_index
}

// Unordered exclusive allocation: block-scan + one atomicAdd for the base.
// Regions are disjoint [offsets[n], offsets[n]+deg[n]) but NOT index-ordered;
// all consumers use offsets[n] + deg[n], never offsets[n+1].
__global__ __launch_bounds__(256) void scan_atomic(const int* __restrict__ deg,
                                                   int* __restrict__ offsets,
                                                   int* __restrict__ gcur, int N) {
    __shared__ int buf[256];
    __shared__ int sbase;
    int tid = threadIdx.x;
    int i = blockIdx.x * 256 + tid;
    int v = (i < N) ? deg[i] : 0;
    int incl = v;
    buf[tid] = v;
    __syncthreads();
#pragma unroll
    for (int off = 1; off < 256; off <<= 1) {
        int t = (tid >= off) ? buf[tid - off] : 0;
        __syncthreads();
        incl += t;
        buf[tid] = incl;
        __syncthreads();
    }
    if (tid == 255) sbase = atomicAdd(gcur, incl);
    __syncthreads();
    if (i < N) offsets[i] = sbase + incl - v;
}

__global__ __launch_bounds__(256) void fill_adj(const int* __restrict__ ei, int E,
                                                const int* __restrict__ offsets,
                                                int* __restrict__ cursor,
                                                int* __restrict__ adj) {
    int e = blockIdx.x * 256 + threadIdx.x;
    if (e < E) {
        int s = ei[e];
        int d = ei[E + e];
        int pos = atomicAdd(&cursor[d], 1);
        adj[offsets[d] + pos] = s;
    }
}

// ---------------- merged prep: x->fp16, weight split images, query norm -----
// Weight image per mat (order Wl0,Wr0,Wl1,Wr1,Wl2,Wr2,Wlin): 4 K-chunks of 32,
// each chunk: hi 4096 + lo 4096 halves. Chunk layout [n][posB*8], posB =
// (gpc + (n&3) + ((n>>2)&3)) & 3 (conflict-free-ish for 32-lane b128 reads).

__global__ __launch_bounds__(256) void prep_all(
    const float* __restrict__ x, const float* __restrict__ query,
    const float* __restrict__ Wl, const float* __restrict__ Wr,
    const float* __restrict__ Wlin, _Float16* __restrict__ xh,
    _Float16* __restrict__ wimg, float* __restrict__ qn, int n8, int SB, int WB) {
    int b = blockIdx.x;
    int tid = threadIdx.x;
    if (b < SB) {
        // role 1: x -> fp16 hi
        int i = b * 256 + tid;
        if (i < n8) {
            const float4* x4 = (const float4*)x;
            float4 u = x4[(size_t)i * 2], v = x4[(size_t)i * 2 + 1];
            float f[8] = {u.x, u.y, u.z, u.w, v.x, v.y, v.z, v.w};
            half8 h;
#pragma unroll
            for (int j = 0; j < 8; ++j) h[j] = (_Float16)f[j];
            *(half8*)(xh + (size_t)i * 8) = h;
        }
    } else if (b < SB + WB) {
        // role 2: weight split + chunk-image packing
        int gidx = (b - SB) * 256 + tid;
        if (gidx < 7 * 2048) {
            int mat = gidx / 2048;
            int rem = gidx - mat * 2048;
            int n = rem >> 4;
            int g = rem & 15;
            const float* src = (mat == 6) ? Wlin
                             : ((mat & 1) ? Wr + (mat >> 1) * H * H
                                          : Wl + (mat >> 1) * H * H);
            const float* p = src + n * H + g * 8;
            half8 h, l;
#pragma unroll
            for (int j = 0; j < 8; ++j) {
                float v = p[j];
                _Float16 hh = (_Float16)v;
                h[j] = hh;
                l[j] = (_Float16)(v - (float)hh);
            }
            int kc4 = g >> 2, gpc = g & 3;
            int posB = (gpc + (n & 3) + ((n >> 2) & 3)) & 3;
            size_t base = (size_t)mat * 32768 + (size_t)kc4 * 8192 + n * 32 + posB * 8;
            *(half8*)(wimg + base) = h;
            *(half8*)(wimg + base + 4096) = l;
        }
    } else {
        // role 3: query normalization
        int g = b - SB - WB;
        __shared__ float part[4];
        float v = (tid < 128) ? query[g * H + tid] : 0.f;
        float ss = v * v;
#pragma unroll
        for (int off = 32; off > 0; off >>= 1) ss += __shfl_xor(ss, off, 64);
        if ((tid & 63) == 0) part[tid >> 6] = ss;
        __syncthreads();
        float tot = part[0] + part[1];
        if (tid < 128) qn[g * H + tid] = v / fmaxf(sqrtf(tot), 1e-12f);
    }
}

// ---------------- fused layer: hi-gather-max + dual GEMM + bias + relu -----
// Y = relu(segmax(X) @ Wl^T + bias + X @ Wr^T), activations fp16 hi-only,
// weights split hi/lo (2 MFMAs per A-fragment: ah*bh + ah*bl).
// Block 256 = 4 waves; tile 64 rows x 128 cols; K=32 B-chunks (4 per pass).
// LDS: sU 16 KB (m full-K image / x 64-k chunk) + sB 8 KB+8 KB = 32 KB
// -> 5 blocks/CU. Gather: 16 lanes/row, 2 rows concurrent x 4-deep unroll.

__global__ __launch_bounds__(256) void layer_fused2(
    const half8* __restrict__ Xh, const int* __restrict__ deg,
    const int* __restrict__ offsets, const int* __restrict__ adj,
    const _Float16* __restrict__ Bimg, const float* __restrict__ bias,
    _Float16* __restrict__ Yh, int N) {
    __shared__ __align__(16) _Float16 sU[8192];  // m image (full K) / x chunk
    __shared__ __align__(16) _Float16 sB[8192];  // B chunk hi(4096)+lo(4096)

    int tid = threadIdx.x;
    int w = tid >> 6;
    int lane = tid & 63;
    int l31 = lane & 31;
    int lhi = lane >> 5;
    int ws = w >> 1;  // row stripe (32 rows)
    int wc = w & 1;   // col half (64 cols)
    int n0 = blockIdx.x * 64;

    // ---- Phase G: hi-only gather segment-max, 2 rows in flight ----
    {
        int lf = tid & 15;
        int grp = tid >> 4;  // 16 groups x 16 lanes
        const _Float16 ni = (_Float16)(-INFINITY);
        const half8 ninf = {ni, ni, ni, ni, ni, ni, ni, ni};
        const half8 hz = {(_Float16)0.f, (_Float16)0.f, (_Float16)0.f, (_Float16)0.f,
                          (_Float16)0.f, (_Float16)0.f, (_Float16)0.f, (_Float16)0.f};
#pragma unroll
        for (int pp = 0; pp < 2; ++pp) {
            int rowA = grp * 4 + pp * 2;
            int rowB = rowA + 1;
            int nA = n0 + rowA, nB = n0 + rowB;
            int eA = 0, dA = 0, eB = 0, dB = 0;
            if (nA < N) { eA = offsets[nA]; dA = deg[nA]; }
            if (nB < N) { eB = offsets[nB]; dB = deg[nB]; }
            half8 a0 = ninf, a1 = ninf, b0 = ninf, b1 = ninf;
            int itm = dA > dB ? dA : dB;
            for (int base = 0; base < itm; base += 4) {
                bool doA = base < dA, doB = base < dB;
                half8 vA[4], vB[4];
                if (doA) {
#pragma unroll
                    for (int u = 0; u < 4; ++u) {
                        int ee = base + u;
                        int idx = adj[eA + (ee < dA ? ee : dA - 1)];
                        vA[u] = Xh[(size_t)idx * 16 + lf];
                    }
                }
                if (doB) {
#pragma unroll
                    for (int u = 0; u < 4; ++u) {
                        int ee = base + u;
                        int idx = adj[eB + (ee < dB ? ee : dB - 1)];
                        vB[u] = Xh[(size_t)idx * 16 + lf];
                    }
                }
                if (doA) {
                    a0 = h8max(a0, h8max(vA[0], vA[2]));
                    a1 = h8max(a1, h8max(vA[1], vA[3]));
                }
                if (doB) {
                    b0 = h8max(b0, h8max(vB[0], vB[2]));
                    b1 = h8max(b1, h8max(vB[1], vB[3]));
                }
            }
            half8 bestA = (dA > 0) ? h8max(a0, a1) : hz;
            half8 bestB = (dB > 0) ? h8max(b0, b1) : hz;
            *(half8*)&sU[rowA * 128 + (lf ^ (rowA & 15)) * 8] = bestA;
            *(half8*)&sU[rowB * 128 + (lf ^ (rowB & 15)) * 8] = bestB;
        }
    }
    __syncthreads();

    f32x16 acc[2];
#pragma unroll
    for (int nt = 0; nt < 2; ++nt) {
        float bv = bias[wc * 64 + nt * 32 + l31];
#pragma unroll
        for (int r = 0; r < 16; ++r) acc[nt][r] = bv;
    }

    int rl = ws * 32 + l31;  // this lane's A row within the tile

    // ---- Pass 0: m @ Wl^T (A = m image, 16-col XOR -> 2-way free) ----
    for (int kc4 = 0; kc4 < 4; ++kc4) {
        if (kc4) __syncthreads();
        {
            const half8* bsrc = (const half8*)(Bimg + (size_t)kc4 * 8192);
            half8* bdst = (half8*)sB;
#pragma unroll
            for (int i = 0; i < 4; ++i) bdst[tid + i * 256] = bsrc[tid + i * 256];
        }
        __syncthreads();
#pragma unroll
        for (int ks = 0; ks < 2; ++ks) {
            int g16 = kc4 * 4 + ks * 2 + lhi;
            int posA = g16 ^ (rl & 15);
            half8 ah = *(const half8*)&sU[rl * 128 + posA * 8];
#pragma unroll
            for (int nt = 0; nt < 2; ++nt) {
                int n = wc * 64 + nt * 32 + l31;
                int gpc = ks * 2 + lhi;
                int posB = (gpc + (n & 3) + ((n >> 2) & 3)) & 3;
                half8 bh = *(const half8*)&sB[n * 32 + posB * 8];
                half8 bl = *(const half8*)&sB[4096 + n * 32 + posB * 8];
                acc[nt] = __builtin_amdgcn_mfma_f32_32x32x16_f16(ah, bh, acc[nt], 0, 0, 0);
                acc[nt] = __builtin_amdgcn_mfma_f32_32x32x16_f16(ah, bl, acc[nt], 0, 0, 0);
            }
        }
    }

    // ---- Pass 1: x @ Wr^T (x 64-k chunks, stride-72 conflict-free) ----
    for (int kc4 = 0; kc4 < 4; ++kc4) {
        __syncthreads();
        {
            const half8* bsrc = (const half8*)(Bimg + 32768 + (size_t)kc4 * 8192);
            half8* bdst = (half8*)sB;
#pragma unroll
            for (int i = 0; i < 4; ++i) bdst[tid + i * 256] = bsrc[tid + i * 256];
        }
        if ((kc4 & 1) == 0) {
            int kc64 = kc4 >> 1;
#pragma unroll
            for (int i = 0; i < 2; ++i) {
                int idx = tid + i * 256;  // [0,512)
                int row = idx >> 3;       // [0,64)
                int gp8 = idx & 7;
                int n = n0 + row;
                half8 h = {(_Float16)0.f, (_Float16)0.f, (_Float16)0.f, (_Float16)0.f,
                           (_Float16)0.f, (_Float16)0.f, (_Float16)0.f, (_Float16)0.f};
                if (n < N) h = Xh[(size_t)n * 16 + kc64 * 8 + gp8];
                int pos8 = (gp8 + (row & 7) + ((row >> 3) & 7)) & 7;
                *(half8*)&sU[row * 72 + pos8 * 8] = h;
            }
        }
        __syncthreads();
#pragma unroll
        for (int ks = 0; ks < 2; ++ks) {
            int gp8 = (kc4 & 1) * 4 + ks * 2 + lhi;
            int posA8 = (gp8 + (rl & 7) + ((rl >> 3) & 7)) & 7;
            half8 ah = *(const half8*)&sU[rl * 72 + posA8 * 8];
#pragma unroll
            for (int nt = 0; nt < 2; ++nt) {
                int n = wc * 64 + nt * 32 + l31;
                int gpc = ks * 2 + lhi;
                int posB = (gpc + (n & 3) + ((n >> 2) & 3)) & 3;
                half8 bh = *(const half8*)&sB[n * 32 + posB * 8];
                half8 bl = *(const half8*)&sB[4096 + n * 32 + posB * 8];
                acc[nt] = __builtin_amdgcn_mfma_f32_32x32x16_f16(ah, bh, acc[nt], 0, 0, 0);
                acc[nt] = __builtin_amdgcn_mfma_f32_32x32x16_f16(ah, bl, acc[nt], 0, 0, 0);
            }
        }
    }

    // epilogue: relu + fp16 store. C/D: col=l31(+base), row=(r&3)+8*(r>>2)+4*lhi
#pragma unroll
    for (int r = 0; r < 16; ++r) {
        int row = n0 + ws * 32 + (r & 3) + 8 * (r >> 2) + 4 * lhi;
        if (row < N) {
#pragma unroll
            for (int nt = 0; nt < 2; ++nt) {
                int col = wc * 64 + nt * 32 + l31;
                Yh[(size_t)row * H + col] = (_Float16)fmaxf(acc[nt][r], 0.f);
            }
        }
    }
}

// ---------------- MFMA final linear + cosine, fp16-hi A ----------------
// Block 256 = 4 waves; each wave an independent 32-row stripe x 128 cols
// (nt=4). 128 rows/block. LDS: sA 18 KB (stride-72) + sB 16 KB = 34 KB.

__global__ __launch_bounds__(256) void final_mfma6(
    const half8* __restrict__ Xh, const _Float16* __restrict__ Bimg,  // Wlin
    const float* __restrict__ blin, const float* __restrict__ qn,
    const int* __restrict__ bv, float* __restrict__ out, int N) {
    __shared__ __align__(16) _Float16 sA[9216];  // 128 rows x stride 72
    __shared__ __align__(16) _Float16 sB[8192];

    int tid = threadIdx.x;
    int w = tid >> 6;
    int lane = tid & 63;
    int l31 = lane & 31;
    int lhi = lane >> 5;
    int n0 = blockIdx.x * 128;

    int arow = n0 + w * 32 + l31;
    arow = arow < N ? arow : N - 1;
    int gl = bv[arow];  // stripe's graph ids, indexed by l31

    f32x16 acc[4];
#pragma unroll
    for (int nt = 0; nt < 4; ++nt) {
        float b = blin[nt * 32 + l31];
#pragma unroll
        for (int r = 0; r < 16; ++r) acc[nt][r] = b;
    }

    int rl = w * 32 + l31;

    for (int kc4 = 0; kc4 < 4; ++kc4) {
        if (kc4) __syncthreads();
        {
            const half8* bsrc = (const half8*)(Bimg + (size_t)kc4 * 8192);
            half8* bdst = (half8*)sB;
#pragma unroll
            for (int i = 0; i < 4; ++i) bdst[tid + i * 256] = bsrc[tid + i * 256];
        }
        if ((kc4 & 1) == 0) {
            int kc64 = kc4 >> 1;
#pragma unroll
            for (int i = 0; i < 4; ++i) {
                int idx = tid + i * 256;  // [0,1024)
                int row = idx >> 3;       // [0,128)
                int gp8 = idx & 7;
                int n = n0 + row;
                half8 h = {(_Float16)0.f, (_Float16)0.f, (_Float16)0.f, (_Float16)0.f,
                           (_Float16)0.f, (_Float16)0.f, (_Float16)0.f, (_Float16)0.f};
                if (n < N) h = Xh[(size_t)n * 16 + kc64 * 8 + gp8];
                int pos8 = (gp8 + (row & 7) + ((row >> 3) & 7)) & 7;
                *(half8*)&sA[row * 72 + pos8 * 8] = h;
            }
        }
        __syncthreads();
#pragma unroll
        for (int ks = 0; ks < 2; ++ks) {
            int gp8 = (kc4 & 1) * 4 + ks * 2 + lhi;
            int posA8 = (gp8 + (rl & 7) + ((rl >> 3) & 7)) & 7;
            half8 ah = *(const half8*)&sA[rl * 72 + posA8 * 8];
#pragma unroll
            for (int nt = 0; nt < 4; ++nt) {
                int n = nt * 32 + l31;
                int gpc = ks * 2 + lhi;
                int posB = (gpc + (n & 3) + ((n >> 2) & 3)) & 3;
                half8 bh = *(const half8*)&sB[n * 32 + posB * 8];
                half8 bl = *(const half8*)&sB[4096 + n * 32 + posB * 8];
                acc[nt] = __builtin_amdgcn_mfma_f32_32x32x16_f16(ah, bh, acc[nt], 0, 0, 0);
                acc[nt] = __builtin_amdgcn_mfma_f32_32x32x16_f16(ah, bl, acc[nt], 0, 0, 0);
            }
        }
    }

    // cosine epilogue: row rloc owned by 32 lanes (l31); xor<=16 stays in group
#pragma unroll
    for (int r = 0; r < 16; ++r) {
        int rloc = (r & 3) + 8 * (r >> 2) + 4 * lhi;
        int row = n0 + w * 32 + rloc;
        int g = __shfl(gl, rloc, 32);  // stripe-row rloc's graph id
        float ss = 0.f, sd = 0.f;
#pragma unroll
        for (int nt = 0; nt < 4; ++nt) {
            float y = acc[nt][r];
            float q = qn[(size_t)g * H + nt * 32 + l31];
            ss = fmaf(y, y, ss);
            sd = fmaf(y, q, sd);
        }
#pragma unroll
        for (int off = 1; off <= 16; off <<= 1) {
            ss += __shfl_xor(ss, off, 64);
            sd += __shfl_xor(sd, off, 64);
        }
        if (l31 == 0 && row < N) out[row] = sd / fmaxf(sqrtf(ss), 1e-12f);
    }
}

// ---------------- launch ----------------

extern "C" void kernel_launch(void* const* d_in, const int* in_sizes, int n_in,
                              void* d_out, int out_size, void* d_ws, size_t ws_size,
                              hipStream_t stream) {
    const float* x = (const float*)d_in[0];
    const float* query = (const float*)d_in[1];
    const float* Wl = (const float*)d_in[2];
    const float* bl = (const float*)d_in[3];
    const float* Wr = (const float*)d_in[4];
    const float* Wlin = (const float*)d_in[5];
    const float* blin = (const float*)d_in[6];
    const int* ei = (const int*)d_in[7];
    const int* bv = (const int*)d_in[8];
    float* out = (float*)d_out;

    const int N = in_sizes[0] / H;
    const int E = in_sizes[7] / 2;
    const int G = in_sizes[1] / H;

    char* p = (char*)d_ws;
    auto alloc = [&](size_t bytes) {
        char* r = p;
        p += (bytes + 255) & ~(size_t)255;
        return r;
    };
    int* deg = (int*)alloc((size_t)(2 * N + 1) * sizeof(int));  // deg|cursor|gcur
    int* cursor = deg + N;
    int* gcur = deg + 2 * N;
    int* offsets = (int*)alloc((size_t)N * sizeof(int));
    int* adj = (int*)alloc((size_t)E * sizeof(int));
    float* qn = (float*)alloc((size_t)G * H * sizeof(float));
    _Float16* wimg = (_Float16*)alloc((size_t)7 * 32768 * sizeof(_Float16));
    size_t actH = (size_t)N * H * sizeof(_Float16);
    _Float16* xah = (_Float16*)alloc(actH);
    _Float16* xbh = (_Float16*)alloc(actH);

    hipMemsetAsync(deg, 0, (size_t)(2 * N + 1) * sizeof(int), stream);
    hist_deg<<<(E + 255) / 256, 256, 0, stream>>>(ei, E, deg);
    scan_atomic<<<(N + 255) / 256, 256, 0, stream>>>(deg, offsets, gcur, N);
    fill_adj<<<(E + 255) / 256, 256, 0, stream>>>(ei, E, offsets, cursor, adj);

    const int n8 = N * H / 8;
    const int SB = (n8 + 255) / 256;
    const int WB = (7 * 2048 + 255) / 256;
    prep_all<<<SB + WB + G, 256, 0, stream>>>(x, query, Wl, Wr, Wlin, xah, wimg,
                                              qn, n8, SB, WB);

    const int NGm = (N + 63) / 64;    // fused layer blocks
    const int NGf = (N + 127) / 128;  // final blocks

    layer_fused2<<<NGm, 256, 0, stream>>>(
        (const half8*)xah, deg, offsets, adj, wimg + (size_t)0 * 65536,
        bl + 0 * H, xbh, N);
    layer_fused2<<<NGm, 256, 0, stream>>>(
        (const half8*)xbh, deg, offsets, adj, wimg + (size_t)1 * 65536,
        bl + 1 * H, xah, N);
    layer_fused2<<<NGm, 256, 0, stream>>>(
        (const half8*)xah, deg, offsets, adj, wimg + (size_t)2 * 65536,
        bl + 2 * H, xbh, N);
    final_mfma6<<<NGf, 256, 0, stream>>>(
        (const half8*)xbh, wimg + (size_t)6 * 32768, blin, qn, bv, out, N);
}

// Round 11
// 280.935 us; speedup vs baseline: 1.3985x; 1.0149x over previous
//
#include <hip/hip_runtime.h>
#include <math.h>

#define H 128

typedef _Float16 half8 __attribute__((ext_vector_type(8)));
typedef float f32x16 __attribute__((ext_vector_type(16)));
typedef int int4v __attribute__((ext_vector_type(4)));

__device__ __forceinline__ half8 h8max(half8 a, half8 b) {
#if defined(__has_builtin) && __has_builtin(__builtin_elementwise_max)
    return __builtin_elementwise_max(a, b);
#else
    half8 r;
#pragma unroll
    for (int j = 0; j < 8; ++j) r[j] = a[j] > b[j] ? a[j] : b[j];
    return r;
#endif
}

__device__ __forceinline__ half8 h8shfl_xor(half8 v, int mask) {
    int4v iv;
    __builtin_memcpy(&iv, &v, 16);
#pragma unroll
    for (int j = 0; j < 4; ++j) iv[j] = __shfl_xor(iv[j], mask, 64);
    half8 r;
    __builtin_memcpy(&r, &iv, 16);
    return r;
}

// ---------------- CSR build ----------------

// Unordered exclusive allocation: block-scan + one atomicAdd for the base.
// Regions are disjoint [offsets[n], offsets[n]+deg[n]) but NOT index-ordered;
// all consumers use offsets[n] + deg[n], never offsets[n+1].
__global__ __launch_bounds__(256) void scan_atomic(const int* __restrict__ deg,
                                                   int* __restrict__ offsets,
                                                   int* __restrict__ gcur, int N) {
    __shared__ int buf[256];
    __shared__ int sbase;
    int tid = threadIdx.x;
    int i = blockIdx.x * 256 + tid;
    int v = (i < N) ? deg[i] : 0;
    int incl = v;
    buf[tid] = v;
    __syncthreads();
#pragma unroll
    for (int off = 1; off < 256; off <<= 1) {
        int t = (tid >= off) ? buf[tid - off] : 0;
        __syncthreads();
        incl += t;
        buf[tid] = incl;
        __syncthreads();
    }
    if (tid == 255) sbase = atomicAdd(gcur, incl);
    __syncthreads();
    if (i < N) offsets[i] = sbase + incl - v;
}

__global__ __launch_bounds__(256) void fill_adj(const int* __restrict__ ei, int E,
                                                const int* __restrict__ offsets,
                                                int* __restrict__ cursor,
                                                int* __restrict__ adj) {
    int e = blockIdx.x * 256 + threadIdx.x;
    if (e < E) {
        int s = ei[e];
        int d = ei[E + e];
        int pos = atomicAdd(&cursor[d], 1);
        adj[offsets[d] + pos] = s;
    }
}

// ---------------- merged prep: deg-hist, x->fp16, weight images, query ------
// Weight image per mat (order Wl0,Wr0,Wl1,Wr1,Wl2,Wr2,Wlin): 4 K-chunks of 32,
// each chunk: hi 4096 + lo 4096 halves. Chunk layout [n][posB*8], posB =
// (gpc + (n&3) + ((n>>2)&3)) & 3.

__global__ __launch_bounds__(256) void prep_all(
    const int* __restrict__ ei, int E, int* __restrict__ deg,
    const float* __restrict__ x, const float* __restrict__ query,
    const float* __restrict__ Wl, const float* __restrict__ Wr,
    const float* __restrict__ Wlin, _Float16* __restrict__ xh,
    _Float16* __restrict__ wimg, float* __restrict__ qn, int n8, int HB, int SB,
    int WB) {
    int b = blockIdx.x;
    int tid = threadIdx.x;
    if (b < HB) {
        // role 0: degree histogram
        int e = b * 256 + tid;
        if (e < E) atomicAdd(&deg[ei[E + e]], 1);
    } else if (b < HB + SB) {
        // role 1: x -> fp16 hi
        int i = (b - HB) * 256 + tid;
        if (i < n8) {
            const float4* x4 = (const float4*)x;
            float4 u = x4[(size_t)i * 2], v = x4[(size_t)i * 2 + 1];
            float f[8] = {u.x, u.y, u.z, u.w, v.x, v.y, v.z, v.w};
            half8 h;
#pragma unroll
            for (int j = 0; j < 8; ++j) h[j] = (_Float16)f[j];
            *(half8*)(xh + (size_t)i * 8) = h;
        }
    } else if (b < HB + SB + WB) {
        // role 2: weight split + chunk-image packing
        int gidx = (b - HB - SB) * 256 + tid;
        if (gidx < 7 * 2048) {
            int mat = gidx / 2048;
            int rem = gidx - mat * 2048;
            int n = rem >> 4;
            int g = rem & 15;
            const float* src = (mat == 6) ? Wlin
                             : ((mat & 1) ? Wr + (mat >> 1) * H * H
                                          : Wl + (mat >> 1) * H * H);
            const float* p = src + n * H + g * 8;
            half8 h, l;
#pragma unroll
            for (int j = 0; j < 8; ++j) {
                float v = p[j];
                _Float16 hh = (_Float16)v;
                h[j] = hh;
                l[j] = (_Float16)(v - (float)hh);
            }
            int kc4 = g >> 2, gpc = g & 3;
            int posB = (gpc + (n & 3) + ((n >> 2) & 3)) & 3;
            size_t base = (size_t)mat * 32768 + (size_t)kc4 * 8192 + n * 32 + posB * 8;
            *(half8*)(wimg + base) = h;
            *(half8*)(wimg + base + 4096) = l;
        }
    } else {
        // role 3: query normalization
        int g = b - HB - SB - WB;
        __shared__ float part[4];
        float v = (tid < 128) ? query[g * H + tid] : 0.f;
        float ss = v * v;
#pragma unroll
        for (int off = 32; off > 0; off >>= 1) ss += __shfl_xor(ss, off, 64);
        if ((tid & 63) == 0) part[tid >> 6] = ss;
        __syncthreads();
        float tot = part[0] + part[1];
        if (tid < 128) qn[g * H + tid] = v / fmaxf(sqrtf(tot), 1e-12f);
    }
}

// ---------------- fused layer: hi-gather-max + dual GEMM + bias + relu -----
// Y = relu(segmax(X) @ Wl^T + bias + X @ Wr^T), activations fp16 hi-only,
// weights split hi/lo (2 MFMAs per A-fragment: ah*bh + ah*bl).
// Block 256 = 4 waves; tile 64 rows x 128 cols; K=32 B-chunks (4 per pass).
// LDS: sU 16 KB (m full-K image / x 64-k chunk) + sB 16 KB = 32 KB
// -> 5 blocks/CU.
// Gather: WAVE-PER-NODE. 64 lanes = 4 neighbors (sub) x 16 lanes (lf),
// unroll 4 -> 16 neighbor-rows in flight; loop bound ceil(d/16) is
// wave-uniform (zero divergence); OOB neighbors clamp to d-1 (dupes are
// max-neutral, L1-resident). Cross-sub reduce = shfl_xor 16,32.

__global__ __launch_bounds__(256) void layer_fused3(
    const half8* __restrict__ Xh, const int* __restrict__ deg,
    const int* __restrict__ offsets, const int* __restrict__ adj,
    const _Float16* __restrict__ Bimg, const float* __restrict__ bias,
    _Float16* __restrict__ Yh, int N) {
    __shared__ __align__(16) _Float16 sU[8192];  // m image (full K) / x chunk
    __shared__ __align__(16) _Float16 sB[8192];  // B chunk hi(4096)+lo(4096)

    int tid = threadIdx.x;
    int w = tid >> 6;
    int lane = tid & 63;
    int l31 = lane & 31;
    int lhi = lane >> 5;
    int ws = w >> 1;  // row stripe (32 rows)
    int wc = w & 1;   // col half (64 cols)
    int n0 = blockIdx.x * 64;

    // ---- Phase G: wave-per-node hi-only gather segment-max ----
    {
        int sub = lane >> 4;  // neighbor slot 0..3
        int lf = lane & 15;   // feature granule
        const _Float16 ni = (_Float16)(-INFINITY);
        const half8 ninf = {ni, ni, ni, ni, ni, ni, ni, ni};
        const half8 hz = {(_Float16)0.f, (_Float16)0.f, (_Float16)0.f, (_Float16)0.f,
                          (_Float16)0.f, (_Float16)0.f, (_Float16)0.f, (_Float16)0.f};
        // lane-parallel preload of this wave's 16 nodes' e0/deg
        int nd = n0 + w * 16 + lf;
        int ndc = nd < N ? nd : N - 1;
        int e0v = offsets[ndc];
        int degv = (nd < N) ? deg[ndc] : 0;

        for (int i = 0; i < 16; ++i) {
            int e0 = __shfl(e0v, i, 64);
            int d = __shfl(degv, i, 64);
            int row = w * 16 + i;
            half8 acc = ninf;
            for (int base = 0; base < d; base += 16) {
                half8 v[4];
#pragma unroll
                for (int q = 0; q < 4; ++q) {
                    int j = base + q * 4 + sub;
                    int idx = adj[e0 + (j < d ? j : d - 1)];
                    v[q] = Xh[(size_t)idx * 16 + lf];
                }
                acc = h8max(acc, h8max(h8max(v[0], v[1]), h8max(v[2], v[3])));
            }
            // cross-sub reduce (lanes lf, lf+16, lf+32, lf+48)
            acc = h8max(acc, h8shfl_xor(acc, 16));
            acc = h8max(acc, h8shfl_xor(acc, 32));
            if (d == 0) acc = hz;
            if (sub == 0) *(half8*)&sU[row * 128 + (lf ^ (row & 15)) * 8] = acc;
        }
    }
    __syncthreads();

    f32x16 acc[2];
#pragma unroll
    for (int nt = 0; nt < 2; ++nt) {
        float bv = bias[wc * 64 + nt * 32 + l31];
#pragma unroll
        for (int r = 0; r < 16; ++r) acc[nt][r] = bv;
    }

    int rl = ws * 32 + l31;  // this lane's A row within the tile

    // ---- Pass 0: m @ Wl^T (A = m image, 16-col XOR -> 2-way free) ----
    for (int kc4 = 0; kc4 < 4; ++kc4) {
        if (kc4) __syncthreads();
        {
            const half8* bsrc = (const half8*)(Bimg + (size_t)kc4 * 8192);
            half8* bdst = (half8*)sB;
#pragma unroll
            for (int i = 0; i < 4; ++i) bdst[tid + i * 256] = bsrc[tid + i * 256];
        }
        __syncthreads();
#pragma unroll
        for (int ks = 0; ks < 2; ++ks) {
            int g16 = kc4 * 4 + ks * 2 + lhi;
            int posA = g16 ^ (rl & 15);
            half8 ah = *(const half8*)&sU[rl * 128 + posA * 8];
#pragma unroll
            for (int nt = 0; nt < 2; ++nt) {
                int n = wc * 64 + nt * 32 + l31;
                int gpc = ks * 2 + lhi;
                int posB = (gpc + (n & 3) + ((n >> 2) & 3)) & 3;
                half8 bh = *(const half8*)&sB[n * 32 + posB * 8];
                half8 bl = *(const half8*)&sB[4096 + n * 32 + posB * 8];
                acc[nt] = __builtin_amdgcn_mfma_f32_32x32x16_f16(ah, bh, acc[nt], 0, 0, 0);
                acc[nt] = __builtin_amdgcn_mfma_f32_32x32x16_f16(ah, bl, acc[nt], 0, 0, 0);
            }
        }
    }

    // ---- Pass 1: x @ Wr^T (x 64-k chunks, stride-72 conflict-free) ----
    for (int kc4 = 0; kc4 < 4; ++kc4) {
        __syncthreads();
        {
            const half8* bsrc = (const half8*)(Bimg + 32768 + (size_t)kc4 * 8192);
            half8* bdst = (half8*)sB;
#pragma unroll
            for (int i = 0; i < 4; ++i) bdst[tid + i * 256] = bsrc[tid + i * 256];
        }
        if ((kc4 & 1) == 0) {
            int kc64 = kc4 >> 1;
#pragma unroll
            for (int i = 0; i < 2; ++i) {
                int idx = tid + i * 256;  // [0,512)
                int row = idx >> 3;       // [0,64)
                int gp8 = idx & 7;
                int n = n0 + row;
                half8 h = {(_Float16)0.f, (_Float16)0.f, (_Float16)0.f, (_Float16)0.f,
                           (_Float16)0.f, (_Float16)0.f, (_Float16)0.f, (_Float16)0.f};
                if (n < N) h = Xh[(size_t)n * 16 + kc64 * 8 + gp8];
                int pos8 = (gp8 + (row & 7) + ((row >> 3) & 7)) & 7;
                *(half8*)&sU[row * 72 + pos8 * 8] = h;
            }
        }
        __syncthreads();
#pragma unroll
        for (int ks = 0; ks < 2; ++ks) {
            int gp8 = (kc4 & 1) * 4 + ks * 2 + lhi;
            int posA8 = (gp8 + (rl & 7) + ((rl >> 3) & 7)) & 7;
            half8 ah = *(const half8*)&sU[rl * 72 + posA8 * 8];
#pragma unroll
            for (int nt = 0; nt < 2; ++nt) {
                int n = wc * 64 + nt * 32 + l31;
                int gpc = ks * 2 + lhi;
                int posB = (gpc + (n & 3) + ((n >> 2) & 3)) & 3;
                half8 bh = *(const half8*)&sB[n * 32 + posB * 8];
                half8 bl = *(const half8*)&sB[4096 + n * 32 + posB * 8];
                acc[nt] = __builtin_amdgcn_mfma_f32_32x32x16_f16(ah, bh, acc[nt], 0, 0, 0);
                acc[nt] = __builtin_amdgcn_mfma_f32_32x32x16_f16(ah, bl, acc[nt], 0, 0, 0);
            }
        }
    }

    // epilogue: relu + fp16 store. C/D: col=l31(+base), row=(r&3)+8*(r>>2)+4*lhi
#pragma unroll
    for (int r = 0; r < 16; ++r) {
        int row = n0 + ws * 32 + (r & 3) + 8 * (r >> 2) + 4 * lhi;
        if (row < N) {
#pragma unroll
            for (int nt = 0; nt < 2; ++nt) {
                int col = wc * 64 + nt * 32 + l31;
                Yh[(size_t)row * H + col] = (_Float16)fmaxf(acc[nt][r], 0.f);
            }
        }
    }
}

// ---------------- MFMA final linear + cosine, fp16-hi A ----------------
// Block 256 = 4 waves; each wave an independent 32-row stripe x 128 cols
// (nt=4). 128 rows/block. LDS: sA 18 KB (stride-72) + sB 16 KB = 34 KB.

__global__ __launch_bounds__(256) void final_mfma6(
    const half8* __restrict__ Xh, const _Float16* __restrict__ Bimg,  // Wlin
    const float* __restrict__ blin, const float* __restrict__ qn,
    const int* __restrict__ bv, float* __restrict__ out, int N) {
    __shared__ __align__(16) _Float16 sA[9216];  // 128 rows x stride 72
    __shared__ __align__(16) _Float16 sB[8192];

    int tid = threadIdx.x;
    int w = tid >> 6;
    int lane = tid & 63;
    int l31 = lane & 31;
    int lhi = lane >> 5;
    int n0 = blockIdx.x * 128;

    int arow = n0 + w * 32 + l31;
    arow = arow < N ? arow : N - 1;
    int gl = bv[arow];  // stripe's graph ids, indexed by l31

    f32x16 acc[4];
#pragma unroll
    for (int nt = 0; nt < 4; ++nt) {
        float b = blin[nt * 32 + l31];
#pragma unroll
        for (int r = 0; r < 16; ++r) acc[nt][r] = b;
    }

    int rl = w * 32 + l31;

    for (int kc4 = 0; kc4 < 4; ++kc4) {
        if (kc4) __syncthreads();
        {
            const half8* bsrc = (const half8*)(Bimg + (size_t)kc4 * 8192);
            half8* bdst = (half8*)sB;
#pragma unroll
            for (int i = 0; i < 4; ++i) bdst[tid + i * 256] = bsrc[tid + i * 256];
        }
        if ((kc4 & 1) == 0) {
            int kc64 = kc4 >> 1;
#pragma unroll
            for (int i = 0; i < 4; ++i) {
                int idx = tid + i * 256;  // [0,1024)
                int row = idx >> 3;       // [0,128)
                int gp8 = idx & 7;
                int n = n0 + row;
                half8 h = {(_Float16)0.f, (_Float16)0.f, (_Float16)0.f, (_Float16)0.f,
                           (_Float16)0.f, (_Float16)0.f, (_Float16)0.f, (_Float16)0.f};
                if (n < N) h = Xh[(size_t)n * 16 + kc64 * 8 + gp8];
                int pos8 = (gp8 + (row & 7) + ((row >> 3) & 7)) & 7;
                *(half8*)&sA[row * 72 + pos8 * 8] = h;
            }
        }
        __syncthreads();
#pragma unroll
        for (int ks = 0; ks < 2; ++ks) {
            int gp8 = (kc4 & 1) * 4 + ks * 2 + lhi;
            int posA8 = (gp8 + (rl & 7) + ((rl >> 3) & 7)) & 7;
            half8 ah = *(const half8*)&sA[rl * 72 + posA8 * 8];
#pragma unroll
            for (int nt = 0; nt < 4; ++nt) {
                int n = nt * 32 + l31;
                int gpc = ks * 2 + lhi;
                int posB = (gpc + (n & 3) + ((n >> 2) & 3)) & 3;
                half8 bh = *(const half8*)&sB[n * 32 + posB * 8];
                half8 bl = *(const half8*)&sB[4096 + n * 32 + posB * 8];
                acc[nt] = __builtin_amdgcn_mfma_f32_32x32x16_f16(ah, bh, acc[nt], 0, 0, 0);
                acc[nt] = __builtin_amdgcn_mfma_f32_32x32x16_f16(ah, bl, acc[nt], 0, 0, 0);
            }
        }
    }

    // cosine epilogue: row rloc owned by 32 lanes (l31); xor<=16 stays in group
#pragma unroll
    for (int r = 0; r < 16; ++r) {
        int rloc = (r & 3) + 8 * (r >> 2) + 4 * lhi;
        int row = n0 + w * 32 + rloc;
        int g = __shfl(gl, rloc, 32);  // stripe-row rloc's graph id
        float ss = 0.f, sd = 0.f;
#pragma unroll
        for (int nt = 0; nt < 4; ++nt) {
            float y = acc[nt][r];
            float q = qn[(size_t)g * H + nt * 32 + l31];
            ss = fmaf(y, y, ss);
            sd = fmaf(y, q, sd);
        }
#pragma unroll
        for (int off = 1; off <= 16; off <<= 1) {
            ss += __shfl_xor(ss, off, 64);
            sd += __shfl_xor(sd, off, 64);
        }
        if (l31 == 0 && row < N) out[row] = sd / fmaxf(sqrtf(ss), 1e-12f);
    }
}

// ---------------- launch ----------------

extern "C" void kernel_launch(void* const* d_in, const int* in_sizes, int n_in,
                              void* d_out, int out_size, void* d_ws, size_t ws_size,
                              hipStream_t stream) {
    const float* x = (const float*)d_in[0];
    const float* query = (const float*)d_in[1];
    const float* Wl = (const float*)d_in[2];
    const float* bl = (const float*)d_in[3];
    const float* Wr = (const float*)d_in[4];
    const float* Wlin = (const float*)d_in[5];
    const float* blin = (const float*)d_in[6];
    const int* ei = (const int*)d_in[7];
    const int* bv = (const int*)d_in[8];
    float* out = (float*)d_out;

    const int N = in_sizes[0] / H;
    const int E = in_sizes[7] / 2;
    const int G = in_sizes[1] / H;

    char* p = (char*)d_ws;
    auto alloc = [&](size_t bytes) {
        char* r = p;
        p += (bytes + 255) & ~(size_t)255;
        return r;
    };
    int* deg = (int*)alloc((size_t)(2 * N + 1) * sizeof(int));  // deg|cursor|gcur
    int* cursor = deg + N;
    int* gcur = deg + 2 * N;
    int* offsets = (int*)alloc((size_t)N * sizeof(int));
    int* adj = (int*)alloc((size_t)E * sizeof(int));
    float* qn = (float*)alloc((size_t)G * H * sizeof(float));
    _Float16* wimg = (_Float16*)alloc((size_t)7 * 32768 * sizeof(_Float16));
    size_t actH = (size_t)N * H * sizeof(_Float16);
    _Float16* xah = (_Float16*)alloc(actH);
    _Float16* xbh = (_Float16*)alloc(actH);

    hipMemsetAsync(deg, 0, (size_t)(2 * N + 1) * sizeof(int), stream);

    const int n8 = N * H / 8;
    const int HB = (E + 255) / 256;
    const int SB = (n8 + 255) / 256;
    const int WB = (7 * 2048 + 255) / 256;
    prep_all<<<HB + SB + WB + G, 256, 0, stream>>>(ei, E, deg, x, query, Wl, Wr,
                                                   Wlin, xah, wimg, qn, n8, HB,
                                                   SB, WB);
    scan_atomic<<<(N + 255) / 256, 256, 0, stream>>>(deg, offsets, gcur, N);
    fill_adj<<<(E + 255) / 256, 256, 0, stream>>>(ei, E, offsets, cursor, adj);

    const int NGm = (N + 63) / 64;    // fused layer blocks
    const int NGf = (N + 127) / 128;  // final blocks

    layer_fused3<<<NGm, 256, 0, stream>>>(
        (const half8*)xah, deg, offsets, adj, wimg + (size_t)0 * 65536,
        bl + 0 * H, xbh, N);
    layer_fused3<<<NGm, 256, 0, stream>>>(
        (const half8*)xbh, deg, offsets, adj, wimg + (size_t)1 * 65536,
        bl + 1 * H, xah, N);
    layer_fused3<<<NGm, 256, 0, stream>>>(
        (const half8*)xah, deg, offsets, adj, wimg + (size_t)2 * 65536,
        bl + 2 * H, xbh, N);
    final_mfma6<<<NGf, 256, 0, stream>>>(
        (const half8*)xbh, wimg + (size_t)6 * 32768, blin, qn, bv, out, N);
}